// Round 1
// baseline (104.790 us; speedup 1.0000x reference)
//
#include <hip/hip_runtime.h>
#include <hip/hip_bf16.h>

// Problem constants
#define NTOK 2048
#define TOPK 2
#define HS   512
#define FFN  2048
#define NE   8
#define TASSIGN (NTOK*TOPK)   // 4096
#define BM 64
#define PADMAX 4608           // 4096 + 8*64
#define MAXTILES 72

typedef __attribute__((ext_vector_type(8))) short bf16x8;
typedef __attribute__((ext_vector_type(4))) float f32x4;

// ws layout (byte offsets)
static const size_t OFF_XBF  = 0;          // [NTOK*HS] bf16          = 2,097,152
static const size_t OFF_WT   = 2097152;    // [NE*FFN*HS] bf16        = 16,777,216 (w1T, later reused for w2T)
static const size_t OFF_H    = 18874368;   // [PADMAX*FFN] bf16       = 18,874,368
static const size_t OFF_OUTV = 37748736;   // [PADMAX*HS] f32         = 9,437,184
static const size_t OFF_RT   = 47185920;   // rowtok [PADMAX] int     = 18,432
static const size_t OFF_HROF = 47204352;   // hr_of_assign [TASSIGN]  = 16,384
static const size_t OFF_TE   = 47220736;   // tile_e [MAXTILES] int
static const size_t OFF_TR0  = 47221056;   // tile_r0 [MAXTILES] int
// total ~47.2 MB

__device__ __forceinline__ unsigned short f2bf(float f) {
    union { __hip_bfloat16 h; unsigned short u; } v;
    v.h = __float2bfloat16(f);
    return v.u;
}

__device__ __forceinline__ int swz(int r, int byte_off) {
    return byte_off ^ ((r & 7) << 4);
}

// ---- x fp32 -> bf16 ----
__global__ void k_xcvt(const float* __restrict__ x, unsigned short* __restrict__ xbf) {
    int i = (blockIdx.x * 256 + threadIdx.x) * 4;
    float4 v = *(const float4*)(x + i);
    ushort4 o;
    o.x = f2bf(v.x); o.y = f2bf(v.y); o.z = f2bf(v.z); o.w = f2bf(v.w);
    *(ushort4*)(xbf + i) = o;
}

// ---- transpose+convert: in [E][R][C] f32 -> out [E][C][R] bf16 ----
__global__ void k_transpose(const float* __restrict__ in, unsigned short* __restrict__ out,
                            int R, int C) {
    __shared__ unsigned short t[32][33];
    int e = blockIdx.z;
    int rb = blockIdx.y * 32, cb = blockIdx.x * 32;
    int tx = threadIdx.x, ty = threadIdx.y;
    const float* ip = in + (size_t)e * R * C;
    unsigned short* op = out + (size_t)e * C * R;
#pragma unroll
    for (int i = 0; i < 4; i++) {
        int r = ty + i * 8;
        t[r][tx] = f2bf(ip[(size_t)(rb + r) * C + cb + tx]);
    }
    __syncthreads();
#pragma unroll
    for (int i = 0; i < 4; i++) {
        int c = ty + i * 8;
        op[(size_t)(cb + c) * R + rb + tx] = t[tx][c];
    }
}

// ---- setup: counting sort of assignments by expert, padded segments, tile tables ----
__global__ void k_setup(const int* __restrict__ ei, const float* __restrict__ ew,
                        int* __restrict__ rowtok, int* __restrict__ hrof,
                        int* __restrict__ tile_e, int* __restrict__ tile_r0) {
    __shared__ int cnt[NE], offpad[NE], cur[NE];
    int tid = threadIdx.x;
    for (int i = tid; i < PADMAX; i += 256) rowtok[i] = -1;
    if (tid < NE) cnt[tid] = 0;
    __syncthreads();
    for (int a = tid; a < TASSIGN; a += 256) atomicAdd(&cnt[ei[a]], 1);
    __syncthreads();
    if (tid == 0) {
        int o = 0, t = 0;
        for (int e = 0; e < NE; e++) {
            offpad[e] = o;
            cur[e] = 0;
            for (int r = 0; r < cnt[e]; r += BM) { tile_e[t] = e; tile_r0[t] = o + r; t++; }
            o += (cnt[e] + BM - 1) / BM * BM;
        }
        for (; t < MAXTILES; t++) { tile_e[t] = -1; tile_r0[t] = 0; }
    }
    __syncthreads();
    for (int a = tid; a < TASSIGN; a += 256) {
        int e = ei[a];
        int r = atomicAdd(&cur[e], 1);
        int hr = offpad[e] + r;
        rowtok[hr] = a >> 1;      // token = assignment / TOPK
        hrof[a] = hr;
    }
}

// ---- GEMM1: H[hr] = gelu(x[token(hr)] @ w1[e])  (M=64 tiles, N=FFN, K=HS) ----
__global__ __launch_bounds__(256) void k_gemm1(
        const unsigned short* __restrict__ xbf, const unsigned short* __restrict__ w1T,
        unsigned short* __restrict__ H, const int* __restrict__ rowtok,
        const int* __restrict__ tile_e, const int* __restrict__ tile_r0) {
    int mt = blockIdx.y;
    int e = tile_e[mt];
    if (e < 0) return;
    int hr0 = tile_r0[mt];
    int ct = blockIdx.x;                 // col tile: 0..FFN/64-1

    __shared__ int4 Asv[512];            // 8KB: A tile [64][64] bf16, swizzled
    __shared__ int4 Bsv[512];            // 8KB: B^T tile [64 cols][64 k] bf16, swizzled
    char* As = (char*)Asv;
    char* Bs = (char*)Bsv;

    int tid = threadIdx.x;
    int lane = tid & 63, wave = tid >> 6;
    int wm = wave >> 1, wn = wave & 1;

    // staging slots: idx = p*256+tid -> row r=idx>>3, 16B chunk c8=idx&7
    const char* asrc[2]; const char* bsrc[2];
    char* adst[2]; char* bdst[2];
    int atok[2];
#pragma unroll
    for (int p = 0; p < 2; p++) {
        int idx = p * 256 + tid;
        int r = idx >> 3, c8 = idx & 7;
        int token = rowtok[hr0 + r];
        atok[p] = token;
        asrc[p] = (const char*)(xbf + (size_t)(token < 0 ? 0 : token) * HS + c8 * 8);
        bsrc[p] = (const char*)(w1T + ((size_t)e * FFN + ct * 64 + r) * HS + c8 * 8);
        adst[p] = As + swz(r, r * 128 + c8 * 16);
        bdst[p] = Bs + swz(r, r * 128 + c8 * 16);
    }

    f32x4 acc[2][2] = {};
#pragma unroll 1
    for (int kt = 0; kt < HS; kt += 64) {
#pragma unroll
        for (int p = 0; p < 2; p++) {
            int4 va = make_int4(0, 0, 0, 0);
            if (atok[p] >= 0) va = *(const int4*)(asrc[p] + kt * 2);
            *(int4*)adst[p] = va;
            *(int4*)bdst[p] = *(const int4*)(bsrc[p] + kt * 2);
        }
        __syncthreads();
#pragma unroll
        for (int kk = 0; kk < 64; kk += 32) {
            bf16x8 af[2], bfr[2];
#pragma unroll
            for (int f = 0; f < 2; f++) {
                int ar = wm * 32 + f * 16 + (lane & 15);
                af[f] = *(const bf16x8*)(As + swz(ar, ar * 128 + kk * 2 + (lane >> 4) * 16));
                int bc = wn * 32 + f * 16 + (lane & 15);
                bfr[f] = *(const bf16x8*)(Bs + swz(bc, bc * 128 + kk * 2 + (lane >> 4) * 16));
            }
#pragma unroll
            for (int i = 0; i < 2; i++)
#pragma unroll
                for (int j = 0; j < 2; j++)
                    acc[i][j] = __builtin_amdgcn_mfma_f32_16x16x32_bf16(af[i], bfr[j], acc[i][j], 0, 0, 0);
        }
        __syncthreads();
    }
    // epilogue: exact gelu, store bf16
#pragma unroll
    for (int i = 0; i < 2; i++)
#pragma unroll
        for (int j = 0; j < 2; j++)
#pragma unroll
            for (int q = 0; q < 4; q++) {
                int row = wm * 32 + i * 16 + (lane >> 4) * 4 + q;
                int col = ct * 64 + wn * 32 + j * 16 + (lane & 15);
                float v = acc[i][j][q];
                float g = 0.5f * v * (1.0f + erff(v * 0.70710678118f));
                H[(size_t)(hr0 + row) * FFN + col] = f2bf(g);
            }
}

// ---- GEMM2: outv[hr] = H[hr] @ w2[e]  (M=64 tiles, N=HS, K=FFN) ----
__global__ __launch_bounds__(256) void k_gemm2(
        const unsigned short* __restrict__ H, const unsigned short* __restrict__ w2T,
        float* __restrict__ outv,
        const int* __restrict__ tile_e, const int* __restrict__ tile_r0) {
    int mt = blockIdx.y;
    int e = tile_e[mt];
    if (e < 0) return;
    int hr0 = tile_r0[mt];
    int ct = blockIdx.x;                 // col tile: 0..HS/64-1

    __shared__ int4 Asv[512];
    __shared__ int4 Bsv[512];
    char* As = (char*)Asv;
    char* Bs = (char*)Bsv;

    int tid = threadIdx.x;
    int lane = tid & 63, wave = tid >> 6;
    int wm = wave >> 1, wn = wave & 1;

    const char* asrc[2]; const char* bsrc[2];
    char* adst[2]; char* bdst[2];
#pragma unroll
    for (int p = 0; p < 2; p++) {
        int idx = p * 256 + tid;
        int r = idx >> 3, c8 = idx & 7;
        asrc[p] = (const char*)(H + (size_t)(hr0 + r) * FFN + c8 * 8);
        bsrc[p] = (const char*)(w2T + ((size_t)e * HS + ct * 64 + r) * FFN + c8 * 8);
        adst[p] = As + swz(r, r * 128 + c8 * 16);
        bdst[p] = Bs + swz(r, r * 128 + c8 * 16);
    }

    f32x4 acc[2][2] = {};
#pragma unroll 1
    for (int kt = 0; kt < FFN; kt += 64) {
#pragma unroll
        for (int p = 0; p < 2; p++) {
            *(int4*)adst[p] = *(const int4*)(asrc[p] + kt * 2);
            *(int4*)bdst[p] = *(const int4*)(bsrc[p] + kt * 2);
        }
        __syncthreads();
#pragma unroll
        for (int kk = 0; kk < 64; kk += 32) {
            bf16x8 af[2], bfr[2];
#pragma unroll
            for (int f = 0; f < 2; f++) {
                int ar = wm * 32 + f * 16 + (lane & 15);
                af[f] = *(const bf16x8*)(As + swz(ar, ar * 128 + kk * 2 + (lane >> 4) * 16));
                int bc = wn * 32 + f * 16 + (lane & 15);
                bfr[f] = *(const bf16x8*)(Bs + swz(bc, bc * 128 + kk * 2 + (lane >> 4) * 16));
            }
#pragma unroll
            for (int i = 0; i < 2; i++)
#pragma unroll
                for (int j = 0; j < 2; j++)
                    acc[i][j] = __builtin_amdgcn_mfma_f32_16x16x32_bf16(af[i], bfr[j], acc[i][j], 0, 0, 0);
        }
        __syncthreads();
    }
#pragma unroll
    for (int i = 0; i < 2; i++)
#pragma unroll
        for (int j = 0; j < 2; j++)
#pragma unroll
            for (int q = 0; q < 4; q++) {
                int row = wm * 32 + i * 16 + (lane >> 4) * 4 + q;
                int col = ct * 64 + wn * 32 + j * 16 + (lane & 15);
                outv[(size_t)(hr0 + row) * HS + col] = acc[i][j][q];
            }
}

// ---- combine: y[t] = w0*o0 + w1*o1 ; buffer[t][e_k] = o_k (dup experts -> sum) ----
__global__ void k_combine(const float* __restrict__ outv, const int* __restrict__ ei,
                          const float* __restrict__ ew, const int* __restrict__ hrof,
                          float* __restrict__ y, float* __restrict__ buf) {
    int g = blockIdx.x * 256 + threadIdx.x;   // over NTOK*HS
    int t = g >> 9, col = g & (HS - 1);
    int a0 = 2 * t, a1 = 2 * t + 1;
    int h0 = hrof[a0], h1 = hrof[a1];
    float o0 = outv[(size_t)h0 * HS + col];
    float o1 = outv[(size_t)h1 * HS + col];
    float w0 = ew[a0], w1 = ew[a1];
    y[g] = w0 * o0 + w1 * o1;
    int e0 = ei[a0], e1 = ei[a1];
    float* bt = buf + (size_t)t * NE * HS + col;
    if (e0 == e1) {
        bt[(size_t)e0 * HS] = o0 + o1;
    } else {
        bt[(size_t)e0 * HS] = o0;
        bt[(size_t)e1 * HS] = o1;
    }
}

extern "C" void kernel_launch(void* const* d_in, const int* in_sizes, int n_in,
                              void* d_out, int out_size, void* d_ws, size_t ws_size,
                              hipStream_t stream) {
    const float* x  = (const float*)d_in[0];
    const float* ew = (const float*)d_in[1];
    const int*   ei = (const int*)d_in[2];
    const float* w1 = (const float*)d_in[3];
    const float* w2 = (const float*)d_in[4];

    char* ws = (char*)d_ws;
    unsigned short* xbf  = (unsigned short*)(ws + OFF_XBF);
    unsigned short* wT   = (unsigned short*)(ws + OFF_WT);   // w1T then w2T (reused)
    unsigned short* Hb   = (unsigned short*)(ws + OFF_H);
    float*          outv = (float*)(ws + OFF_OUTV);
    int*            rowtok = (int*)(ws + OFF_RT);
    int*            hrof   = (int*)(ws + OFF_HROF);
    int*            tile_e = (int*)(ws + OFF_TE);
    int*            tile_r0= (int*)(ws + OFF_TR0);

    float* y   = (float*)d_out;
    float* buf = (float*)d_out + (size_t)NTOK * HS;

    // zero outputs (buffer is sparse; y fully overwritten but cheap to include)
    hipMemsetAsync(d_out, 0, (size_t)out_size * sizeof(float), stream);

    // x -> bf16
    k_xcvt<<<(NTOK * HS / 4 + 255) / 256, 256, 0, stream>>>(x, xbf);
    // w1 [E][HS][FFN] -> w1T [E][FFN][HS] bf16
    k_transpose<<<dim3(FFN / 32, HS / 32, NE), dim3(32, 8), 0, stream>>>(w1, wT, HS, FFN);
    // grouping
    k_setup<<<1, 256, 0, stream>>>(ei, ew, rowtok, hrof, tile_e, tile_r0);
    // GEMM1 + gelu -> H (bf16)
    k_gemm1<<<dim3(FFN / 64, MAXTILES), 256, 0, stream>>>(xbf, wT, Hb, rowtok, tile_e, tile_r0);
    // w2 [E][FFN][HS] -> w2T [E][HS][FFN] bf16 (reuses wT region; stream-ordered after gemm1)
    k_transpose<<<dim3(HS / 32, FFN / 32, NE), dim3(32, 8), 0, stream>>>(w2, wT, FFN, HS);
    // GEMM2 -> outv (f32)
    k_gemm2<<<dim3(HS / 64, MAXTILES), 256, 0, stream>>>(Hb, wT, outv, tile_e, tile_r0);
    // combine into y and buffer
    k_combine<<<NTOK * HS / 256, 256, 0, stream>>>(outv, ei, ew, hrof, y, buf);
}